// Round 3
// baseline (881.082 us; speedup 1.0000x reference)
//
#include <hip/hip_runtime.h>

#define N_NODES 50000
#define N_EDGES 1600000
#define D_IN 192
#define D_HID 128

#define NSLICE 8
#define SLICE_SZ ((N_NODES + NSLICE - 1) / NSLICE)   // 6250

typedef __bf16 bf16x8 __attribute__((ext_vector_type(8)));
typedef float f32x4 __attribute__((ext_vector_type(4)));
typedef float f32x2 __attribute__((ext_vector_type(2)));

__device__ __forceinline__ unsigned short f2b(float x) {
    unsigned u = __builtin_bit_cast(unsigned, x);
    u += 0x7FFFu + ((u >> 16) & 1u);          // round-to-nearest-even
    return (unsigned short)(u >> 16);
}
__device__ __forceinline__ float blo(unsigned u) {   // low bf16 of packed pair
    return __builtin_bit_cast(float, u << 16);
}
__device__ __forceinline__ float bhi(unsigned u) {   // high bf16
    return __builtin_bit_cast(float, u & 0xFFFF0000u);
}

// ---------------- CSR build ----------------

// hist + per-edge rank (within-dst order). rank write is linear/coalesced.
__global__ void hist_kernel(const int* __restrict__ dst, int E,
                            int* __restrict__ cnt, int* __restrict__ rank) {
    int e = blockIdx.x * blockDim.x + threadIdx.x;
    if (e < E) rank[e] = atomicAdd(&cnt[dst[e]], 1);
}

// ---- 3-phase multi-block exclusive scan over cnt[0..n) ----
__global__ __launch_bounds__(256) void scanA(const int* __restrict__ cnt,
                                             int* __restrict__ bsum, int n) {
    int i = blockIdx.x * 256 + threadIdx.x;
    int v = (i < n) ? cnt[i] : 0;
#pragma unroll
    for (int off = 32; off > 0; off >>= 1) v += __shfl_down(v, off);
    __shared__ int ws[4];
    if ((threadIdx.x & 63) == 0) ws[threadIdx.x >> 6] = v;
    __syncthreads();
    if (threadIdx.x == 0) bsum[blockIdx.x] = ws[0] + ws[1] + ws[2] + ws[3];
}

__global__ __launch_bounds__(256) void scanB(const int* __restrict__ bsum,
                                             int* __restrict__ boff,
                                             int* __restrict__ row_ptr, int nb, int n) {
    __shared__ int s[256];
    int tid = threadIdx.x;
    int v = (tid < nb) ? bsum[tid] : 0;
    s[tid] = v;
    __syncthreads();
    for (int off = 1; off < 256; off <<= 1) {
        int add = (tid >= off) ? s[tid - off] : 0;
        __syncthreads();
        s[tid] += add;
        __syncthreads();
    }
    if (tid < nb) boff[tid] = (tid > 0) ? s[tid - 1] : 0;
    if (tid == 0) row_ptr[n] = s[255];
}

__global__ __launch_bounds__(256) void scanC(const int* __restrict__ cnt,
                                             const int* __restrict__ boff,
                                             int* __restrict__ row_ptr,
                                             float* __restrict__ dhis, int n) {
    __shared__ int s[256];
    int tid = threadIdx.x;
    int i = blockIdx.x * 256 + tid;
    int c = (i < n) ? cnt[i] : 0;
    s[tid] = c;
    __syncthreads();
    for (int off = 1; off < 256; off <<= 1) {
        int add = (tid >= off) ? s[tid - off] : 0;
        __syncthreads();
        s[tid] += add;
        __syncthreads();
    }
    if (i < n) {
        int pre = boff[blockIdx.x] + s[tid] - c;   // exclusive prefix
        row_ptr[i] = pre;
        dhis[i] = rsqrtf((float)c + 1.0f);
    }
}

// Slice-partitioned scatter: block b -> dst slice (b%8), edge chunk (b/8).
// Writes edata = {src, dhis[src]} so agg needs no dependent dhis gather.
__global__ __launch_bounds__(256) void fill_sliced(
        const int* __restrict__ src, const int* __restrict__ dst,
        const int* __restrict__ rank, const int* __restrict__ row_ptr,
        const float* __restrict__ dhis,
        int2* __restrict__ edata, int E, int nchunks) {
    int slice = blockIdx.x & (NSLICE - 1);
    int chunk = blockIdx.x >> 3;
    int lo = slice * SLICE_SZ;
    int hi = lo + SLICE_SZ;
    int per = (E + nchunks - 1) / nchunks;
    int e0 = chunk * per;
    int e1 = min(e0 + per, E);
    for (int e = e0 + threadIdx.x; e < e1; e += 256) {
        int d = dst[e];
        if (d >= lo && d < hi) {
            int s = src[e];
            edata[row_ptr[d] + rank[e]] =
                make_int2(s, __builtin_bit_cast(int, dhis[s]));
        }
    }
}

// ---------------- weight prep: Wt[j][k] = bf16(W[k][j]) ----------------

__global__ void prep_w(const float* __restrict__ W, unsigned short* __restrict__ Wt, int K) {
    int idx = blockIdx.x * 256 + threadIdx.x;
    if (idx < 128 * K) {
        int j = idx / K, k = idx - j * K;
        Wt[idx] = f2b(W[(size_t)k * 128 + j]);
    }
}

// ---------------- MFMA GEMM: hcomb[M,.] interleaved = bf16(A@W + b) --------
// Output layout per node row (256 ushorts = 512B):
//   ushort idx = (col>>1)*4 + view*2 + (col&1)
// so lane l of agg reads uint2 {view0 pair, view1 pair} for features 2l,2l+1.

__global__ __launch_bounds__(256) void gemm_mfma(
        const float* __restrict__ A, int lda, int K, int Kp,
        const unsigned short* __restrict__ Wt, const float* __restrict__ bias,
        unsigned short* __restrict__ out, int view, int M) {
    __shared__ __align__(16) unsigned short As[64 * 200];   // row stride Kp (<=200)

    int tid = threadIdx.x;
    int row0 = blockIdx.x * 64;

    // ---- stage A panel (64 rows x K) as bf16 ----
    {
        int r = tid >> 2;          // 0..63
        int q = tid & 3;
        int grow = row0 + r;
        int crow = grow < M ? grow : (M - 1);
        int kq = K >> 2;           // 48 or 32
        const float* ap = A + (size_t)crow * lda + q * kq;
        unsigned short* sp = As + r * Kp + q * kq;
        for (int k = 0; k < kq; k += 4) {
            float4 v = *(const float4*)(ap + k);
            sp[k + 0] = f2b(v.x); sp[k + 1] = f2b(v.y);
            sp[k + 2] = f2b(v.z); sp[k + 3] = f2b(v.w);
        }
    }
    __syncthreads();

    int wave = tid >> 6, lane = tid & 63;
    int m = lane & 15, quad = lane >> 4;

    f32x4 acc[8];
#pragma unroll
    for (int g = 0; g < 8; ++g) acc[g] = (f32x4){0.f, 0.f, 0.f, 0.f};

    int nsteps = K >> 5;           // 6 or 4
    for (int ks = 0; ks < nsteps; ++ks) {
        int k0 = ks * 32 + quad * 8;
        bf16x8 af = *(const bf16x8*)(As + (wave * 16 + m) * Kp + k0);
#pragma unroll
        for (int g = 0; g < 8; ++g) {
            bf16x8 bfr = *(const bf16x8*)(Wt + (size_t)(g * 16 + m) * K + k0);
            acc[g] = __builtin_amdgcn_mfma_f32_16x16x32_bf16(af, bfr, acc[g], 0, 0, 0);
        }
    }

    // ---- epilogue: C/D layout col=lane&15, row=quad*4+reg ----
#pragma unroll
    for (int g = 0; g < 8; ++g) {
        int col = g * 16 + m;
        float bv = bias[col];
        int ci = ((col >> 1) << 2) + (view << 1) + (col & 1);
#pragma unroll
        for (int r = 0; r < 4; ++r) {
            int grow = row0 + wave * 16 + quad * 4 + r;
            if (grow < M) out[(size_t)grow * 256 + ci] = f2b(acc[g][r] + bv);
        }
    }
}

// ---------------- fused dual-view aggregation + combine + relu ----------------
// One wave per dst node; lane l handles features 2l, 2l+1 of both views via
// one uint2 gather per edge.

__global__ __launch_bounds__(256) void agg_kernel(
        const unsigned* __restrict__ hcomb,       // [n][128] uints interleaved
        const int* __restrict__ row_ptr, const int2* __restrict__ edata,
        const float* __restrict__ dhis, const float* __restrict__ D_inv,
        float* __restrict__ out_q, float* __restrict__ out_p, int n) {
    int wave = threadIdx.x >> 6, lane = threadIdx.x & 63;
    int d = blockIdx.x * 4 + wave;
    if (d >= n) return;

    int e0 = row_ptr[d], e1 = row_ptr[d + 1];
    f32x2 a1 = {0.f, 0.f}, g1 = {0.f, 0.f};
    f32x2 a2 = {0.f, 0.f}, g2 = {0.f, 0.f};

#define EDGE_BODY(u, w) {                                         \
        f32x2 v1 = {blo((u).x), bhi((u).x)};                      \
        f32x2 v2 = {blo((u).y), bhi((u).y)};                      \
        f32x2 wv = {(w), (w)};                                    \
        a1 += v1; g1 = __builtin_elementwise_fma(v1, wv, g1);     \
        a2 += v2; g2 = __builtin_elementwise_fma(v2, wv, g2); }

    int e = e0;
    for (; e + 4 <= e1; e += 4) {
        int4 ea = *(const int4*)(edata + e);
        int4 eb = *(const int4*)(edata + e + 2);
        uint2 u0 = *((const uint2*)(hcomb + ((size_t)ea.x << 7)) + lane);
        uint2 u1 = *((const uint2*)(hcomb + ((size_t)ea.z << 7)) + lane);
        uint2 u2 = *((const uint2*)(hcomb + ((size_t)eb.x << 7)) + lane);
        uint2 u3 = *((const uint2*)(hcomb + ((size_t)eb.z << 7)) + lane);
        float w0 = __builtin_bit_cast(float, ea.y);
        float w1 = __builtin_bit_cast(float, ea.w);
        float w2 = __builtin_bit_cast(float, eb.y);
        float w3 = __builtin_bit_cast(float, eb.w);
        EDGE_BODY(u0, w0); EDGE_BODY(u1, w1);
        EDGE_BODY(u2, w2); EDGE_BODY(u3, w3);
    }
    for (; e < e1; ++e) {
        int2 ed = edata[e];
        uint2 u = *((const uint2*)(hcomb + ((size_t)ed.x << 7)) + lane);
        float w = __builtin_bit_cast(float, ed.y);
        EDGE_BODY(u, w);
    }
#undef EDGE_BODY

    float dh = dhis[d];
    float di = D_inv[d];
    float dh2 = dh * dh;
    f32x2 dhv = {dh, dh}, dh2v = {dh2, dh2}, div = {di, di};

    uint2 us = *((const uint2*)(hcomb + ((size_t)d << 7)) + lane);
    f32x2 s1 = {blo(us.x), bhi(us.x)};
    f32x2 s2 = {blo(us.y), bhi(us.y)};

    f32x2 o1 = __builtin_elementwise_fma(g1, dhv,
               __builtin_elementwise_fma(s1, dh2v, a2 * div));
    f32x2 o2 = __builtin_elementwise_fma(g2, dhv,
               __builtin_elementwise_fma(s2, dh2v, a1 * div));

    f32x2 zero = {0.f, 0.f};
    o1 = __builtin_elementwise_max(o1, zero);
    o2 = __builtin_elementwise_max(o2, zero);
    *(f32x2*)(out_q + (size_t)d * 384 + lane * 2) = o1;
    *(f32x2*)(out_p + (size_t)d * 384 + lane * 2) = o2;
}

// ---------------- launcher ----------------

extern "C" void kernel_launch(void* const* d_in, const int* in_sizes, int n_in,
                              void* d_out, int out_size, void* d_ws, size_t ws_size,
                              hipStream_t stream) {
    const float* x     = (const float*)d_in[0];
    const float* view2 = (const float*)d_in[1];
    const int*   eidx  = (const int*)d_in[2];
    const float* D_inv = (const float*)d_in[3];
    const float* W1 = (const float*)d_in[4];  const float* b1 = (const float*)d_in[5];
    const float* W2 = (const float*)d_in[6];  const float* b2 = (const float*)d_in[7];
    const float* W3 = (const float*)d_in[8];  const float* b3 = (const float*)d_in[9];
    const float* W4 = (const float*)d_in[10]; const float* b4 = (const float*)d_in[11];
    const float* W5 = (const float*)d_in[12]; const float* b5 = (const float*)d_in[13];
    const float* W6 = (const float*)d_in[14]; const float* b6 = (const float*)d_in[15];

    const int n = N_NODES;
    const int E = N_EDGES;
    const int* src  = eidx;
    const int* dstv = eidx + E;

    char* ws = (char*)d_ws;
    size_t off = 0;
    auto alloc = [&](size_t bytes) -> void* {
        void* p = ws + off;
        off += (bytes + 255) & ~(size_t)255;
        return p;
    };
    int*   cnt     = (int*)alloc((size_t)n * 4);
    int*   row_ptr = (int*)alloc((size_t)(n + 1) * 4);
    float* dhis    = (float*)alloc((size_t)n * 4);
    int*   rank    = (int*)alloc((size_t)E * 4);
    int2*  edata   = (int2*)alloc((size_t)E * 8);
    int*   bsum    = (int*)alloc((size_t)256 * 4);
    int*   boff    = (int*)alloc((size_t)256 * 4);
    unsigned short* hcomb = (unsigned short*)alloc((size_t)n * 256 * 2);
    unsigned short* Wt1 = (unsigned short*)alloc((size_t)128 * 192 * 2);
    unsigned short* Wt4 = (unsigned short*)alloc((size_t)128 * 192 * 2);
    unsigned short* Wt2 = (unsigned short*)alloc((size_t)128 * 128 * 2);
    unsigned short* Wt3 = (unsigned short*)alloc((size_t)128 * 128 * 2);
    unsigned short* Wt5 = (unsigned short*)alloc((size_t)128 * 128 * 2);
    unsigned short* Wt6 = (unsigned short*)alloc((size_t)128 * 128 * 2);

    float* qb = (float*)d_out;
    float* pb = qb + (size_t)n * 384;

    // --- CSR build ---
    hipMemsetAsync(cnt, 0, (size_t)n * 4, stream);
    int eblocks = (E + 255) / 256;
    int nb = (n + 255) / 256;      // 196 blocks (<=256 required by scanB)
    hist_kernel<<<eblocks, 256, 0, stream>>>(dstv, E, cnt, rank);
    scanA<<<nb, 256, 0, stream>>>(cnt, bsum, n);
    scanB<<<1, 256, 0, stream>>>(bsum, boff, row_ptr, nb, n);
    scanC<<<nb, 256, 0, stream>>>(cnt, boff, row_ptr, dhis, n);
    int nchunks = 1024;
    fill_sliced<<<nchunks * NSLICE, 256, 0, stream>>>(src, dstv, rank, row_ptr,
                                                      dhis, edata, E, nchunks);

    // --- weight transposes (bf16) ---
    prep_w<<<(128 * 192 + 255) / 256, 256, 0, stream>>>(W1, Wt1, 192);
    prep_w<<<(128 * 192 + 255) / 256, 256, 0, stream>>>(W4, Wt4, 192);
    prep_w<<<(128 * 128 + 255) / 256, 256, 0, stream>>>(W2, Wt2, 128);
    prep_w<<<(128 * 128 + 255) / 256, 256, 0, stream>>>(W3, Wt3, 128);
    prep_w<<<(128 * 128 + 255) / 256, 256, 0, stream>>>(W5, Wt5, 128);
    prep_w<<<(128 * 128 + 255) / 256, 256, 0, stream>>>(W6, Wt6, 128);

    int gblocks = (n + 63) / 64;
    int ablocks = (n + 3) / 4;
    const unsigned* hc = (const unsigned*)hcomb;

    // --- layer 1 ---
    gemm_mfma<<<gblocks, 256, 0, stream>>>(x,     D_IN, 192, 200, Wt1, b1, hcomb, 0, n);
    gemm_mfma<<<gblocks, 256, 0, stream>>>(view2, D_IN, 192, 200, Wt4, b4, hcomb, 1, n);
    agg_kernel<<<ablocks, 256, 0, stream>>>(hc, row_ptr, edata, dhis, D_inv, qb + 0, pb + 0, n);

    // --- layer 2 ---
    gemm_mfma<<<gblocks, 256, 0, stream>>>(qb, 384, 128, 136, Wt2, b2, hcomb, 0, n);
    gemm_mfma<<<gblocks, 256, 0, stream>>>(pb, 384, 128, 136, Wt5, b5, hcomb, 1, n);
    agg_kernel<<<ablocks, 256, 0, stream>>>(hc, row_ptr, edata, dhis, D_inv, qb + 128, pb + 128, n);

    // --- layer 3 ---
    gemm_mfma<<<gblocks, 256, 0, stream>>>(qb + 128, 384, 128, 136, Wt3, b3, hcomb, 0, n);
    gemm_mfma<<<gblocks, 256, 0, stream>>>(pb + 128, 384, 128, 136, Wt6, b6, hcomb, 1, n);
    agg_kernel<<<ablocks, 256, 0, stream>>>(hc, row_ptr, edata, dhis, D_inv, qb + 256, pb + 256, n);
}

// Round 4
// 878.416 us; speedup vs baseline: 1.0030x; 1.0030x over previous
//
#include <hip/hip_runtime.h>

#define N_NODES 50000
#define N_EDGES 1600000
#define D_IN 192
#define D_HID 128

#define NSLICE 8
#define SLICE_SZ ((N_NODES + NSLICE - 1) / NSLICE)   // 6250

typedef __bf16 bf16x8 __attribute__((ext_vector_type(8)));
typedef float f32x4 __attribute__((ext_vector_type(4)));
typedef float f32x2 __attribute__((ext_vector_type(2)));

__device__ __forceinline__ unsigned short f2b(float x) {
    unsigned u = __builtin_bit_cast(unsigned, x);
    u += 0x7FFFu + ((u >> 16) & 1u);          // round-to-nearest-even
    return (unsigned short)(u >> 16);
}
__device__ __forceinline__ float blo(unsigned u) {   // low bf16 of packed pair
    return __builtin_bit_cast(float, u << 16);
}
__device__ __forceinline__ float bhi(unsigned u) {   // high bf16
    return __builtin_bit_cast(float, u & 0xFFFF0000u);
}

// ---------------- CSR build ----------------

// hist + per-edge rank (within-dst order). rank write is linear/coalesced.
__global__ void hist_kernel(const int* __restrict__ dst, int E,
                            int* __restrict__ cnt, int* __restrict__ rank) {
    int e = blockIdx.x * blockDim.x + threadIdx.x;
    if (e < E) rank[e] = atomicAdd(&cnt[dst[e]], 1);
}

// ---- 3-phase multi-block exclusive scan over cnt[0..n) ----
__global__ __launch_bounds__(256) void scanA(const int* __restrict__ cnt,
                                             int* __restrict__ bsum, int n) {
    int i = blockIdx.x * 256 + threadIdx.x;
    int v = (i < n) ? cnt[i] : 0;
#pragma unroll
    for (int off = 32; off > 0; off >>= 1) v += __shfl_down(v, off);
    __shared__ int ws[4];
    if ((threadIdx.x & 63) == 0) ws[threadIdx.x >> 6] = v;
    __syncthreads();
    if (threadIdx.x == 0) bsum[blockIdx.x] = ws[0] + ws[1] + ws[2] + ws[3];
}

__global__ __launch_bounds__(256) void scanB(const int* __restrict__ bsum,
                                             int* __restrict__ boff,
                                             int* __restrict__ row_ptr, int nb, int n) {
    __shared__ int s[256];
    int tid = threadIdx.x;
    int v = (tid < nb) ? bsum[tid] : 0;
    s[tid] = v;
    __syncthreads();
    for (int off = 1; off < 256; off <<= 1) {
        int add = (tid >= off) ? s[tid - off] : 0;
        __syncthreads();
        s[tid] += add;
        __syncthreads();
    }
    if (tid < nb) boff[tid] = (tid > 0) ? s[tid - 1] : 0;
    if (tid == 0) row_ptr[n] = s[255];
}

__global__ __launch_bounds__(256) void scanC(const int* __restrict__ cnt,
                                             const int* __restrict__ boff,
                                             int* __restrict__ row_ptr,
                                             float* __restrict__ dhis, int n) {
    __shared__ int s[256];
    int tid = threadIdx.x;
    int i = blockIdx.x * 256 + tid;
    int c = (i < n) ? cnt[i] : 0;
    s[tid] = c;
    __syncthreads();
    for (int off = 1; off < 256; off <<= 1) {
        int add = (tid >= off) ? s[tid - off] : 0;
        __syncthreads();
        s[tid] += add;
        __syncthreads();
    }
    if (i < n) {
        int pre = boff[blockIdx.x] + s[tid] - c;   // exclusive prefix
        row_ptr[i] = pre;
        dhis[i] = rsqrtf((float)c + 1.0f);
    }
}

// Slice-partitioned scatter: block b -> dst slice (b%8), edge chunk (b/8).
// Writes edata = {src, dhis[src]} so agg needs no dependent dhis gather.
__global__ __launch_bounds__(256) void fill_sliced(
        const int* __restrict__ src, const int* __restrict__ dst,
        const int* __restrict__ rank, const int* __restrict__ row_ptr,
        const float* __restrict__ dhis,
        int2* __restrict__ edata, int E, int nchunks) {
    int slice = blockIdx.x & (NSLICE - 1);
    int chunk = blockIdx.x >> 3;
    int lo = slice * SLICE_SZ;
    int hi = lo + SLICE_SZ;
    int per = (E + nchunks - 1) / nchunks;
    int e0 = chunk * per;
    int e1 = min(e0 + per, E);
    for (int e = e0 + threadIdx.x; e < e1; e += 256) {
        int d = dst[e];
        if (d >= lo && d < hi) {
            int s = src[e];
            edata[row_ptr[d] + rank[e]] =
                make_int2(s, __builtin_bit_cast(int, dhis[s]));
        }
    }
}

// ---------------- weight prep: Wt[j][k] = bf16(W[k][j]) ----------------

__global__ void prep_w(const float* __restrict__ W, unsigned short* __restrict__ Wt, int K) {
    int idx = blockIdx.x * 256 + threadIdx.x;
    if (idx < 128 * K) {
        int j = idx / K, k = idx - j * K;
        Wt[idx] = f2b(W[(size_t)k * 128 + j]);
    }
}

// ---------------- MFMA GEMM: hcomb[M,.] interleaved = bf16(A@W + b) --------
// Output layout per node row (256 ushorts = 512B):
//   ushort idx = (col>>1)*4 + view*2 + (col&1)
// so lane l of agg reads uint2 {view0 pair, view1 pair} for features 2l,2l+1.

__global__ __launch_bounds__(256) void gemm_mfma(
        const float* __restrict__ A, int lda, int K, int Kp,
        const unsigned short* __restrict__ Wt, const float* __restrict__ bias,
        unsigned short* __restrict__ out, int view, int M) {
    __shared__ __align__(16) unsigned short As[64 * 200];   // row stride Kp (<=200)

    int tid = threadIdx.x;
    int row0 = blockIdx.x * 64;

    // ---- stage A panel (64 rows x K) as bf16 ----
    {
        int r = tid >> 2;          // 0..63
        int q = tid & 3;
        int grow = row0 + r;
        int crow = grow < M ? grow : (M - 1);
        int kq = K >> 2;           // 48 or 32
        const float* ap = A + (size_t)crow * lda + q * kq;
        unsigned short* sp = As + r * Kp + q * kq;
        for (int k = 0; k < kq; k += 4) {
            float4 v = *(const float4*)(ap + k);
            sp[k + 0] = f2b(v.x); sp[k + 1] = f2b(v.y);
            sp[k + 2] = f2b(v.z); sp[k + 3] = f2b(v.w);
        }
    }
    __syncthreads();

    int wave = tid >> 6, lane = tid & 63;
    int m = lane & 15, quad = lane >> 4;

    f32x4 acc[8];
#pragma unroll
    for (int g = 0; g < 8; ++g) acc[g] = (f32x4){0.f, 0.f, 0.f, 0.f};

    int nsteps = K >> 5;           // 6 or 4
    for (int ks = 0; ks < nsteps; ++ks) {
        int k0 = ks * 32 + quad * 8;
        bf16x8 af = *(const bf16x8*)(As + (wave * 16 + m) * Kp + k0);
#pragma unroll
        for (int g = 0; g < 8; ++g) {
            bf16x8 bfr = *(const bf16x8*)(Wt + (size_t)(g * 16 + m) * K + k0);
            acc[g] = __builtin_amdgcn_mfma_f32_16x16x32_bf16(af, bfr, acc[g], 0, 0, 0);
        }
    }

    // ---- epilogue: C/D layout col=lane&15, row=quad*4+reg ----
#pragma unroll
    for (int g = 0; g < 8; ++g) {
        int col = g * 16 + m;
        float bv = bias[col];
        int ci = ((col >> 1) << 2) + (view << 1) + (col & 1);
#pragma unroll
        for (int r = 0; r < 4; ++r) {
            int grow = row0 + wave * 16 + quad * 4 + r;
            if (grow < M) out[(size_t)grow * 256 + ci] = f2b(acc[g][r] + bv);
        }
    }
}

// ---------------- fused dual-view aggregation + combine + relu ----------------
// One wave per dst node; lane l handles features 2l, 2l+1 of both views via
// one uint2 gather per edge. 8-edge unroll: all 8 gathers issued before any
// consumption -> ~4KB in flight per wave (latency hiding).

__global__ __launch_bounds__(256) void agg_kernel(
        const unsigned* __restrict__ hcomb,       // [n][128] uints interleaved
        const int* __restrict__ row_ptr, const int2* __restrict__ edata,
        const float* __restrict__ dhis, const float* __restrict__ D_inv,
        float* __restrict__ out_q, float* __restrict__ out_p, int n) {
    int wave = threadIdx.x >> 6, lane = threadIdx.x & 63;
    int d = blockIdx.x * 4 + wave;
    if (d >= n) return;

    const uint2* hc2 = (const uint2*)hcomb;      // [n][64] uint2

    int e0 = row_ptr[d], e1 = row_ptr[d + 1];
    f32x2 a1 = {0.f, 0.f}, g1 = {0.f, 0.f};
    f32x2 a2 = {0.f, 0.f}, g2 = {0.f, 0.f};

#define EDGE_BODY(u, w) {                                         \
        f32x2 v1 = {blo((u).x), bhi((u).x)};                      \
        f32x2 v2 = {blo((u).y), bhi((u).y)};                      \
        f32x2 wv = {(w), (w)};                                    \
        a1 += v1; g1 = __builtin_elementwise_fma(v1, wv, g1);     \
        a2 += v2; g2 = __builtin_elementwise_fma(v2, wv, g2); }
#define BC(i) __builtin_bit_cast(float, i)

    int e = e0;
    for (; e + 8 <= e1; e += 8) {
        int4 ea = *(const int4*)(edata + e);
        int4 eb = *(const int4*)(edata + e + 2);
        int4 ec = *(const int4*)(edata + e + 4);
        int4 ed = *(const int4*)(edata + e + 6);
        uint2 u0 = hc2[((size_t)ea.x << 6) + lane];
        uint2 u1 = hc2[((size_t)ea.z << 6) + lane];
        uint2 u2 = hc2[((size_t)eb.x << 6) + lane];
        uint2 u3 = hc2[((size_t)eb.z << 6) + lane];
        uint2 u4 = hc2[((size_t)ec.x << 6) + lane];
        uint2 u5 = hc2[((size_t)ec.z << 6) + lane];
        uint2 u6 = hc2[((size_t)ed.x << 6) + lane];
        uint2 u7 = hc2[((size_t)ed.z << 6) + lane];
        EDGE_BODY(u0, BC(ea.y)); EDGE_BODY(u1, BC(ea.w));
        EDGE_BODY(u2, BC(eb.y)); EDGE_BODY(u3, BC(eb.w));
        EDGE_BODY(u4, BC(ec.y)); EDGE_BODY(u5, BC(ec.w));
        EDGE_BODY(u6, BC(ed.y)); EDGE_BODY(u7, BC(ed.w));
    }
    for (; e + 4 <= e1; e += 4) {
        int4 ea = *(const int4*)(edata + e);
        int4 eb = *(const int4*)(edata + e + 2);
        uint2 u0 = hc2[((size_t)ea.x << 6) + lane];
        uint2 u1 = hc2[((size_t)ea.z << 6) + lane];
        uint2 u2 = hc2[((size_t)eb.x << 6) + lane];
        uint2 u3 = hc2[((size_t)eb.z << 6) + lane];
        EDGE_BODY(u0, BC(ea.y)); EDGE_BODY(u1, BC(ea.w));
        EDGE_BODY(u2, BC(eb.y)); EDGE_BODY(u3, BC(eb.w));
    }
    for (; e < e1; ++e) {
        int2 ed2 = edata[e];
        uint2 u = hc2[((size_t)ed2.x << 6) + lane];
        EDGE_BODY(u, BC(ed2.y));
    }
#undef EDGE_BODY
#undef BC

    float dh = dhis[d];
    float di = D_inv[d];
    float dh2 = dh * dh;
    f32x2 dhv = {dh, dh}, dh2v = {dh2, dh2}, div = {di, di};

    uint2 us = hc2[((size_t)d << 6) + lane];
    f32x2 s1 = {blo(us.x), bhi(us.x)};
    f32x2 s2 = {blo(us.y), bhi(us.y)};

    f32x2 o1 = __builtin_elementwise_fma(g1, dhv,
               __builtin_elementwise_fma(s1, dh2v, a2 * div));
    f32x2 o2 = __builtin_elementwise_fma(g2, dhv,
               __builtin_elementwise_fma(s2, dh2v, a1 * div));

    f32x2 zero = {0.f, 0.f};
    o1 = __builtin_elementwise_max(o1, zero);
    o2 = __builtin_elementwise_max(o2, zero);
    *(f32x2*)(out_q + (size_t)d * 384 + lane * 2) = o1;
    *(f32x2*)(out_p + (size_t)d * 384 + lane * 2) = o2;
}

// ---------------- launcher ----------------

extern "C" void kernel_launch(void* const* d_in, const int* in_sizes, int n_in,
                              void* d_out, int out_size, void* d_ws, size_t ws_size,
                              hipStream_t stream) {
    const float* x     = (const float*)d_in[0];
    const float* view2 = (const float*)d_in[1];
    const int*   eidx  = (const int*)d_in[2];
    const float* D_inv = (const float*)d_in[3];
    const float* W1 = (const float*)d_in[4];  const float* b1 = (const float*)d_in[5];
    const float* W2 = (const float*)d_in[6];  const float* b2 = (const float*)d_in[7];
    const float* W3 = (const float*)d_in[8];  const float* b3 = (const float*)d_in[9];
    const float* W4 = (const float*)d_in[10]; const float* b4 = (const float*)d_in[11];
    const float* W5 = (const float*)d_in[12]; const float* b5 = (const float*)d_in[13];
    const float* W6 = (const float*)d_in[14]; const float* b6 = (const float*)d_in[15];

    const int n = N_NODES;
    const int E = N_EDGES;
    const int* src  = eidx;
    const int* dstv = eidx + E;

    char* ws = (char*)d_ws;
    size_t off = 0;
    auto alloc = [&](size_t bytes) -> void* {
        void* p = ws + off;
        off += (bytes + 255) & ~(size_t)255;
        return p;
    };
    int*   cnt     = (int*)alloc((size_t)n * 4);
    int*   row_ptr = (int*)alloc((size_t)(n + 1) * 4);
    float* dhis    = (float*)alloc((size_t)n * 4);
    int*   rank    = (int*)alloc((size_t)E * 4);
    int2*  edata   = (int2*)alloc((size_t)E * 8);
    int*   bsum    = (int*)alloc((size_t)256 * 4);
    int*   boff    = (int*)alloc((size_t)256 * 4);
    unsigned short* hcomb = (unsigned short*)alloc((size_t)n * 256 * 2);
    unsigned short* Wt1 = (unsigned short*)alloc((size_t)128 * 192 * 2);
    unsigned short* Wt4 = (unsigned short*)alloc((size_t)128 * 192 * 2);
    unsigned short* Wt2 = (unsigned short*)alloc((size_t)128 * 128 * 2);
    unsigned short* Wt3 = (unsigned short*)alloc((size_t)128 * 128 * 2);
    unsigned short* Wt5 = (unsigned short*)alloc((size_t)128 * 128 * 2);
    unsigned short* Wt6 = (unsigned short*)alloc((size_t)128 * 128 * 2);

    float* qb = (float*)d_out;
    float* pb = qb + (size_t)n * 384;

    // --- CSR build ---
    hipMemsetAsync(cnt, 0, (size_t)n * 4, stream);
    int eblocks = (E + 255) / 256;
    int nb = (n + 255) / 256;      // 196 blocks (<=256 required by scanB)
    hist_kernel<<<eblocks, 256, 0, stream>>>(dstv, E, cnt, rank);
    scanA<<<nb, 256, 0, stream>>>(cnt, bsum, n);
    scanB<<<1, 256, 0, stream>>>(bsum, boff, row_ptr, nb, n);
    scanC<<<nb, 256, 0, stream>>>(cnt, boff, row_ptr, dhis, n);
    int nchunks = 1024;
    fill_sliced<<<nchunks * NSLICE, 256, 0, stream>>>(src, dstv, rank, row_ptr,
                                                      dhis, edata, E, nchunks);

    // --- weight transposes (bf16) ---
    prep_w<<<(128 * 192 + 255) / 256, 256, 0, stream>>>(W1, Wt1, 192);
    prep_w<<<(128 * 192 + 255) / 256, 256, 0, stream>>>(W4, Wt4, 192);
    prep_w<<<(128 * 128 + 255) / 256, 256, 0, stream>>>(W2, Wt2, 128);
    prep_w<<<(128 * 128 + 255) / 256, 256, 0, stream>>>(W3, Wt3, 128);
    prep_w<<<(128 * 128 + 255) / 256, 256, 0, stream>>>(W5, Wt5, 128);
    prep_w<<<(128 * 128 + 255) / 256, 256, 0, stream>>>(W6, Wt6, 128);

    int gblocks = (n + 63) / 64;
    int ablocks = (n + 3) / 4;
    const unsigned* hc = (const unsigned*)hcomb;

    // --- layer 1 ---
    gemm_mfma<<<gblocks, 256, 0, stream>>>(x,     D_IN, 192, 200, Wt1, b1, hcomb, 0, n);
    gemm_mfma<<<gblocks, 256, 0, stream>>>(view2, D_IN, 192, 200, Wt4, b4, hcomb, 1, n);
    agg_kernel<<<ablocks, 256, 0, stream>>>(hc, row_ptr, edata, dhis, D_inv, qb + 0, pb + 0, n);

    // --- layer 2 ---
    gemm_mfma<<<gblocks, 256, 0, stream>>>(qb, 384, 128, 136, Wt2, b2, hcomb, 0, n);
    gemm_mfma<<<gblocks, 256, 0, stream>>>(pb, 384, 128, 136, Wt5, b5, hcomb, 1, n);
    agg_kernel<<<ablocks, 256, 0, stream>>>(hc, row_ptr, edata, dhis, D_inv, qb + 128, pb + 128, n);

    // --- layer 3 ---
    gemm_mfma<<<gblocks, 256, 0, stream>>>(qb + 128, 384, 128, 136, Wt3, b3, hcomb, 0, n);
    gemm_mfma<<<gblocks, 256, 0, stream>>>(pb + 128, 384, 128, 136, Wt6, b6, hcomb, 1, n);
    agg_kernel<<<ablocks, 256, 0, stream>>>(hc, row_ptr, edata, dhis, D_inv, qb + 256, pb + 256, n);
}

// Round 5
// 778.454 us; speedup vs baseline: 1.1318x; 1.1284x over previous
//
#include <hip/hip_runtime.h>

#define N_NODES 50000
#define N_EDGES 1600000
#define D_IN 192
#define D_HID 128

#define NSLICE 8
#define SLICE_SZ ((N_NODES + NSLICE - 1) / NSLICE)   // 6250

typedef __bf16 bf16x8 __attribute__((ext_vector_type(8)));
typedef float f32x4 __attribute__((ext_vector_type(4)));
typedef float f32x2 __attribute__((ext_vector_type(2)));
typedef unsigned short u16x8 __attribute__((ext_vector_type(8)));

__device__ __forceinline__ unsigned short f2b(float x) {
    unsigned u = __builtin_bit_cast(unsigned, x);
    u += 0x7FFFu + ((u >> 16) & 1u);          // round-to-nearest-even
    return (unsigned short)(u >> 16);
}
__device__ __forceinline__ float blo(unsigned u) {   // low bf16 of packed pair
    return __builtin_bit_cast(float, u << 16);
}
__device__ __forceinline__ float bhi(unsigned u) {   // high bf16
    return __builtin_bit_cast(float, u & 0xFFFF0000u);
}
__device__ __forceinline__ bf16x8 pack8(float4 a, float4 b) {
    u16x8 t;
    t[0] = f2b(a.x); t[1] = f2b(a.y); t[2] = f2b(a.z); t[3] = f2b(a.w);
    t[4] = f2b(b.x); t[5] = f2b(b.y); t[6] = f2b(b.z); t[7] = f2b(b.w);
    return __builtin_bit_cast(bf16x8, t);
}

// ---------------- CSR build ----------------

// hist + per-edge rank (within-dst order). rank write is linear/coalesced.
__global__ void hist_kernel(const int* __restrict__ dst, int E,
                            int* __restrict__ cnt, int* __restrict__ rank) {
    int e = blockIdx.x * blockDim.x + threadIdx.x;
    if (e < E) rank[e] = atomicAdd(&cnt[dst[e]], 1);
}

// ---- 3-phase multi-block exclusive scan over cnt[0..n) ----
__global__ __launch_bounds__(256) void scanA(const int* __restrict__ cnt,
                                             int* __restrict__ bsum, int n) {
    int i = blockIdx.x * 256 + threadIdx.x;
    int v = (i < n) ? cnt[i] : 0;
#pragma unroll
    for (int off = 32; off > 0; off >>= 1) v += __shfl_down(v, off);
    __shared__ int ws[4];
    if ((threadIdx.x & 63) == 0) ws[threadIdx.x >> 6] = v;
    __syncthreads();
    if (threadIdx.x == 0) bsum[blockIdx.x] = ws[0] + ws[1] + ws[2] + ws[3];
}

__global__ __launch_bounds__(256) void scanB(const int* __restrict__ bsum,
                                             int* __restrict__ boff,
                                             int* __restrict__ row_ptr, int nb, int n) {
    __shared__ int s[256];
    int tid = threadIdx.x;
    int v = (tid < nb) ? bsum[tid] : 0;
    s[tid] = v;
    __syncthreads();
    for (int off = 1; off < 256; off <<= 1) {
        int add = (tid >= off) ? s[tid - off] : 0;
        __syncthreads();
        s[tid] += add;
        __syncthreads();
    }
    if (tid < nb) boff[tid] = (tid > 0) ? s[tid - 1] : 0;
    if (tid == 0) row_ptr[n] = s[255];
}

__global__ __launch_bounds__(256) void scanC(const int* __restrict__ cnt,
                                             const int* __restrict__ boff,
                                             int* __restrict__ row_ptr,
                                             float* __restrict__ dhis, int n) {
    __shared__ int s[256];
    int tid = threadIdx.x;
    int i = blockIdx.x * 256 + tid;
    int c = (i < n) ? cnt[i] : 0;
    s[tid] = c;
    __syncthreads();
    for (int off = 1; off < 256; off <<= 1) {
        int add = (tid >= off) ? s[tid - off] : 0;
        __syncthreads();
        s[tid] += add;
        __syncthreads();
    }
    if (i < n) {
        int pre = boff[blockIdx.x] + s[tid] - c;   // exclusive prefix
        row_ptr[i] = pre;
        dhis[i] = rsqrtf((float)c + 1.0f);
    }
}

// Slice-partitioned scatter: block b -> dst slice (b%8), edge chunk (b/8).
__global__ __launch_bounds__(256) void fill_sliced(
        const int* __restrict__ src, const int* __restrict__ dst,
        const int* __restrict__ rank, const int* __restrict__ row_ptr,
        int* __restrict__ esrc, int E, int nchunks) {
    int slice = blockIdx.x & (NSLICE - 1);
    int chunk = blockIdx.x >> 3;
    int lo = slice * SLICE_SZ;
    int hi = lo + SLICE_SZ;
    int per = (E + nchunks - 1) / nchunks;
    int e0 = chunk * per;
    int e1 = min(e0 + per, E);
    for (int e = e0 + threadIdx.x; e < e1; e += 256) {
        int d = dst[e];
        if (d >= lo && d < hi) {
            esrc[row_ptr[d] + rank[e]] = src[e];
        }
    }
}

// ---------------- fused weight prep: Wt arena, Wt[j][k] = bf16(W[k][j]) -------
// Arena layout (ushorts): Wt1[24576] Wt4[24576] Wt2[16384] Wt3[16384]
//                         Wt5[16384] Wt6[16384]

__global__ void prep_all(const float* __restrict__ W1, const float* __restrict__ W4,
                         const float* __restrict__ W2, const float* __restrict__ W3,
                         const float* __restrict__ W5, const float* __restrict__ W6,
                         unsigned short* __restrict__ Wt) {
    int idx = blockIdx.x * 256 + threadIdx.x;
    const float* W; int K, base;
    if      (idx <  24576) { W = W1; K = 192; base = 0; }
    else if (idx <  49152) { W = W4; K = 192; base = 24576; }
    else if (idx <  65536) { W = W2; K = 128; base = 49152; }
    else if (idx <  81920) { W = W3; K = 128; base = 65536; }
    else if (idx <  98304) { W = W5; K = 128; base = 81920; }
    else if (idx < 114688) { W = W6; K = 128; base = 98304; }
    else return;
    int r = idx - base;
    int j = r / K, k = r - j * K;
    Wt[idx] = f2b(W[(size_t)k * 128 + j]);
}

// ---------------- dual-view MFMA GEMM ----------------
// Block 256 thr = 4 waves, BM=128 (32 rows/wave, 2 row-frags). grid.y = view.
// B (Wt, bf16 [128][K]) staged ONCE into LDS in fragment-linear order:
//   frag f = (g*ns+ks)*64 + lane  ->  16B at Wlds+f*8  (conflict-free b128 reads)
// A read global->register per wave (each wave owns its rows; no LDS, 1 barrier).
// Out: interleaved hcomb row (256 ushorts): ci = (col>>1)*4 + view*2 + (col&1).

__global__ __launch_bounds__(256) void gemm_dual(
        const float* __restrict__ A0, const float* __restrict__ A1, int lda,
        int K, int ns,
        const unsigned short* __restrict__ Wt0, const unsigned short* __restrict__ Wt1,
        const float* __restrict__ bias0, const float* __restrict__ bias1,
        unsigned short* __restrict__ out, int M) {
    __shared__ __align__(16) unsigned short Wlds[192 * 128];   // up to 48 KB

    int view = blockIdx.y;
    const float* A = view ? A1 : A0;
    const unsigned short* Wt = view ? Wt1 : Wt0;
    const float* bias = view ? bias1 : bias0;

    int tid = threadIdx.x;

    // stage Wt -> LDS in fragment-linear order
    int nfrag = ns * 512;                       // 8 g * ns * 64 lanes
    for (int f = tid; f < nfrag; f += 256) {
        int lane = f & 63;
        int gk = f >> 6;
        int g = gk / ns, ks = gk - g * ns;
        int col = g * 16 + (lane & 15);
        int kpos = ks * 32 + (lane >> 4) * 8;
        *(bf16x8*)(Wlds + (size_t)f * 8) =
            *(const bf16x8*)(Wt + (size_t)col * K + kpos);
    }
    __syncthreads();

    int wave = tid >> 6, lane = tid & 63;
    int m = lane & 15, quad = lane >> 4;
    int row0 = blockIdx.x * 128;

    int rA0 = row0 + wave * 32 + m;
    int rA1 = rA0 + 16;
    int cA0 = rA0 < M ? rA0 : M - 1;
    int cA1 = rA1 < M ? rA1 : M - 1;
    const float* a0 = A + (size_t)cA0 * lda + quad * 8;
    const float* a1 = A + (size_t)cA1 * lda + quad * 8;

    f32x4 acc[2][8];
#pragma unroll
    for (int h = 0; h < 2; ++h)
#pragma unroll
        for (int g = 0; g < 8; ++g) acc[h][g] = (f32x4){0.f, 0.f, 0.f, 0.f};

    const bf16x8* wl = (const bf16x8*)Wlds;
    for (int ks = 0; ks < ns; ++ks) {
        float4 va = *(const float4*)(a0 + ks * 32);
        float4 vb = *(const float4*)(a0 + ks * 32 + 4);
        float4 vc = *(const float4*)(a1 + ks * 32);
        float4 vd = *(const float4*)(a1 + ks * 32 + 4);
        bf16x8 af0 = pack8(va, vb);
        bf16x8 af1 = pack8(vc, vd);
#pragma unroll
        for (int g = 0; g < 8; ++g) {
            bf16x8 bfr = wl[(g * ns + ks) * 64 + lane];
            acc[0][g] = __builtin_amdgcn_mfma_f32_16x16x32_bf16(af0, bfr, acc[0][g], 0, 0, 0);
            acc[1][g] = __builtin_amdgcn_mfma_f32_16x16x32_bf16(af1, bfr, acc[1][g], 0, 0, 0);
        }
    }

    // epilogue: C/D layout col=lane&15, row=quad*4+reg
#pragma unroll
    for (int h = 0; h < 2; ++h) {
#pragma unroll
        for (int g = 0; g < 8; ++g) {
            int col = g * 16 + m;
            float bv = bias[col];
            int ci = ((col >> 1) << 2) + (view << 1) + (col & 1);
#pragma unroll
            for (int r = 0; r < 4; ++r) {
                int grow = row0 + wave * 32 + h * 16 + quad * 4 + r;
                if (grow < M) out[(size_t)grow * 256 + ci] = f2b(acc[h][g][r] + bv);
            }
        }
    }
}

// ---------------- fused dual-view aggregation + combine + relu ----------------
// One wave per dst node; lane l gathers one uint2 (features 2l,2l+1, both views)
// per edge; dhis[s] gathered per edge (L2-hot, 200KB). 8-edge unroll.

__global__ __launch_bounds__(256) void agg_kernel(
        const unsigned* __restrict__ hcomb,       // [n][128] uints interleaved
        const int* __restrict__ row_ptr, const int* __restrict__ esrc,
        const float* __restrict__ dhis, const float* __restrict__ D_inv,
        float* __restrict__ out_q, float* __restrict__ out_p, int n) {
    int wave = threadIdx.x >> 6, lane = threadIdx.x & 63;
    int d = blockIdx.x * 4 + wave;
    if (d >= n) return;

    const uint2* hc2 = (const uint2*)hcomb;      // [n][64] uint2

    int e0 = row_ptr[d], e1 = row_ptr[d + 1];
    f32x2 a1 = {0.f, 0.f}, g1 = {0.f, 0.f};
    f32x2 a2 = {0.f, 0.f}, g2 = {0.f, 0.f};

#define EDGE_BODY(u, w) {                                         \
        f32x2 v1 = {blo((u).x), bhi((u).x)};                      \
        f32x2 v2 = {blo((u).y), bhi((u).y)};                      \
        f32x2 wv = {(w), (w)};                                    \
        a1 += v1; g1 = __builtin_elementwise_fma(v1, wv, g1);     \
        a2 += v2; g2 = __builtin_elementwise_fma(v2, wv, g2); }

    int e = e0;
    for (; e + 8 <= e1; e += 8) {
        int4 sa = *(const int4*)(esrc + e);
        int4 sb = *(const int4*)(esrc + e + 4);
        uint2 u0 = hc2[((size_t)sa.x << 6) + lane];
        uint2 u1 = hc2[((size_t)sa.y << 6) + lane];
        uint2 u2 = hc2[((size_t)sa.z << 6) + lane];
        uint2 u3 = hc2[((size_t)sa.w << 6) + lane];
        uint2 u4 = hc2[((size_t)sb.x << 6) + lane];
        uint2 u5 = hc2[((size_t)sb.y << 6) + lane];
        uint2 u6 = hc2[((size_t)sb.z << 6) + lane];
        uint2 u7 = hc2[((size_t)sb.w << 6) + lane];
        float w0 = dhis[sa.x], w1 = dhis[sa.y], w2 = dhis[sa.z], w3 = dhis[sa.w];
        float w4 = dhis[sb.x], w5 = dhis[sb.y], w6 = dhis[sb.z], w7 = dhis[sb.w];
        EDGE_BODY(u0, w0); EDGE_BODY(u1, w1);
        EDGE_BODY(u2, w2); EDGE_BODY(u3, w3);
        EDGE_BODY(u4, w4); EDGE_BODY(u5, w5);
        EDGE_BODY(u6, w6); EDGE_BODY(u7, w7);
    }
    for (; e + 4 <= e1; e += 4) {
        int4 sa = *(const int4*)(esrc + e);
        uint2 u0 = hc2[((size_t)sa.x << 6) + lane];
        uint2 u1 = hc2[((size_t)sa.y << 6) + lane];
        uint2 u2 = hc2[((size_t)sa.z << 6) + lane];
        uint2 u3 = hc2[((size_t)sa.w << 6) + lane];
        float w0 = dhis[sa.x], w1 = dhis[sa.y], w2 = dhis[sa.z], w3 = dhis[sa.w];
        EDGE_BODY(u0, w0); EDGE_BODY(u1, w1);
        EDGE_BODY(u2, w2); EDGE_BODY(u3, w3);
    }
    for (; e < e1; ++e) {
        int s = esrc[e];
        uint2 u = hc2[((size_t)s << 6) + lane];
        EDGE_BODY(u, dhis[s]);
    }
#undef EDGE_BODY

    float dh = dhis[d];
    float di = D_inv[d];
    float dh2 = dh * dh;
    f32x2 dhv = {dh, dh}, dh2v = {dh2, dh2}, div = {di, di};

    uint2 us = hc2[((size_t)d << 6) + lane];
    f32x2 s1 = {blo(us.x), bhi(us.x)};
    f32x2 s2 = {blo(us.y), bhi(us.y)};

    f32x2 o1 = __builtin_elementwise_fma(g1, dhv,
               __builtin_elementwise_fma(s1, dh2v, a2 * div));
    f32x2 o2 = __builtin_elementwise_fma(g2, dhv,
               __builtin_elementwise_fma(s2, dh2v, a1 * div));

    f32x2 zero = {0.f, 0.f};
    o1 = __builtin_elementwise_max(o1, zero);
    o2 = __builtin_elementwise_max(o2, zero);
    *(f32x2*)(out_q + (size_t)d * 384 + lane * 2) = o1;
    *(f32x2*)(out_p + (size_t)d * 384 + lane * 2) = o2;
}

// ---------------- launcher ----------------

extern "C" void kernel_launch(void* const* d_in, const int* in_sizes, int n_in,
                              void* d_out, int out_size, void* d_ws, size_t ws_size,
                              hipStream_t stream) {
    const float* x     = (const float*)d_in[0];
    const float* view2 = (const float*)d_in[1];
    const int*   eidx  = (const int*)d_in[2];
    const float* D_inv = (const float*)d_in[3];
    const float* W1 = (const float*)d_in[4];  const float* b1 = (const float*)d_in[5];
    const float* W2 = (const float*)d_in[6];  const float* b2 = (const float*)d_in[7];
    const float* W3 = (const float*)d_in[8];  const float* b3 = (const float*)d_in[9];
    const float* W4 = (const float*)d_in[10]; const float* b4 = (const float*)d_in[11];
    const float* W5 = (const float*)d_in[12]; const float* b5 = (const float*)d_in[13];
    const float* W6 = (const float*)d_in[14]; const float* b6 = (const float*)d_in[15];

    const int n = N_NODES;
    const int E = N_EDGES;
    const int* src  = eidx;
    const int* dstv = eidx + E;

    char* ws = (char*)d_ws;
    size_t off = 0;
    auto alloc = [&](size_t bytes) -> void* {
        void* p = ws + off;
        off += (bytes + 255) & ~(size_t)255;
        return p;
    };
    int*   cnt     = (int*)alloc((size_t)n * 4);
    int*   row_ptr = (int*)alloc((size_t)(n + 1) * 4);
    float* dhis    = (float*)alloc((size_t)n * 4);
    int*   rank    = (int*)alloc((size_t)E * 4);
    int*   esrc    = (int*)alloc((size_t)E * 4);
    int*   bsum    = (int*)alloc((size_t)256 * 4);
    int*   boff    = (int*)alloc((size_t)256 * 4);
    unsigned short* hcomb = (unsigned short*)alloc((size_t)n * 256 * 2);
    unsigned short* Wta   = (unsigned short*)alloc((size_t)114688 * 2);   // Wt arena

    unsigned short* Wt1 = Wta + 0;
    unsigned short* Wt4 = Wta + 24576;
    unsigned short* Wt2 = Wta + 49152;
    unsigned short* Wt3 = Wta + 65536;
    unsigned short* Wt5 = Wta + 81920;
    unsigned short* Wt6 = Wta + 98304;

    float* qb = (float*)d_out;
    float* pb = qb + (size_t)n * 384;

    // --- CSR build ---
    hipMemsetAsync(cnt, 0, (size_t)n * 4, stream);
    int eblocks = (E + 255) / 256;
    int nb = (n + 255) / 256;      // 196 blocks (<=256 required by scanB)
    hist_kernel<<<eblocks, 256, 0, stream>>>(dstv, E, cnt, rank);
    scanA<<<nb, 256, 0, stream>>>(cnt, bsum, n);
    scanB<<<1, 256, 0, stream>>>(bsum, boff, row_ptr, nb, n);
    scanC<<<nb, 256, 0, stream>>>(cnt, boff, row_ptr, dhis, n);
    int nchunks = 1024;
    fill_sliced<<<nchunks * NSLICE, 256, 0, stream>>>(src, dstv, rank, row_ptr,
                                                      esrc, E, nchunks);

    // --- weight transposes (bf16), single dispatch ---
    prep_all<<<(114688 + 255) / 256, 256, 0, stream>>>(W1, W4, W2, W3, W5, W6, Wta);

    dim3 ggrid((n + 127) / 128, 2);
    int ablocks = (n + 3) / 4;
    const unsigned* hc = (const unsigned*)hcomb;

    // --- layer 1 ---
    gemm_dual<<<ggrid, 256, 0, stream>>>(x, view2, D_IN, 192, 6, Wt1, Wt4, b1, b4, hcomb, n);
    agg_kernel<<<ablocks, 256, 0, stream>>>(hc, row_ptr, esrc, dhis, D_inv, qb + 0, pb + 0, n);

    // --- layer 2 ---
    gemm_dual<<<ggrid, 256, 0, stream>>>(qb, pb, 384, 128, 4, Wt2, Wt5, b2, b5, hcomb, n);
    agg_kernel<<<ablocks, 256, 0, stream>>>(hc, row_ptr, esrc, dhis, D_inv, qb + 128, pb + 128, n);

    // --- layer 3 ---
    gemm_dual<<<ggrid, 256, 0, stream>>>(qb + 128, pb + 128, 384, 128, 4, Wt3, Wt6, b3, b6, hcomb, n);
    agg_kernel<<<ablocks, 256, 0, stream>>>(hc, row_ptr, esrc, dhis, D_inv, qb + 256, pb + 256, n);
}